// Round 1
// baseline (423.312 us; speedup 1.0000x reference)
//
#include <hip/hip_runtime.h>
#include <hip/hip_bf16.h>

// Problem constants
#define NN 128
#define CC 64
#define TT 128
#define VV 25
#define RR 8
#define HH 12

// ---------------------------------------------------------------------------
// Kernel A: xm[n,c,v] = mean over T of x[n,c,t,v].  One block per (n,c).
// Coalesced float4 reads, LDS float atomics for the per-v accumulation.
// ---------------------------------------------------------------------------
__global__ __launch_bounds__(256) void kA_tmean(const float* __restrict__ x,
                                                float* __restrict__ xm) {
    const int blk = blockIdx.x;            // n*CC + c
    const int tid = threadIdx.x;
    __shared__ float sv[VV];
    if (tid < VV) sv[tid] = 0.f;
    __syncthreads();

    const float4* xb = (const float4*)(x + (size_t)blk * (TT * VV));  // 3200 floats = 800 float4
    for (int i = tid; i < (TT * VV) / 4; i += 256) {
        float4 v4 = xb[i];
        int g = i * 4;
        int v0 = g % VV;
        float vals[4] = {v4.x, v4.y, v4.z, v4.w};
#pragma unroll
        for (int k = 0; k < 4; k++) {
            int v = v0 + k;
            if (v >= VV) v -= VV;
            atomicAdd(&sv[v], vals[k]);
        }
    }
    __syncthreads();
    if (tid < VV) xm[(size_t)blk * VV + tid] = sv[tid] * (1.f / TT);
}

// ---------------------------------------------------------------------------
// Kernel B: per-n small pipeline. One block per n.
//  s[v]   = mean_c xm[n,c,v]
//  h[j]   = relu(se_w1 @ s + se_b1)
//  a[v]   = sigmoid(se_w2 @ h + se_b2)          -> a_out
//  x1[r,v]= w1 @ xm + b1 ; x2 likewise
//  rel[r,u,v] = tanh(x1[r,u] - x2[r,v])         -> rel_out
// ---------------------------------------------------------------------------
__global__ __launch_bounds__(256) void kB_small(
    const float* __restrict__ xm,
    const float* __restrict__ w1, const float* __restrict__ b1,
    const float* __restrict__ w2, const float* __restrict__ b2,
    const float* __restrict__ sw1, const float* __restrict__ sb1,
    const float* __restrict__ sw2, const float* __restrict__ sb2,
    float* __restrict__ a_out, float* __restrict__ rel_out) {
    const int n = blockIdx.x;
    const int tid = threadIdx.x;
    __shared__ float lxm[CC * VV];   // 1600
    __shared__ float ls[VV];
    __shared__ float lh[HH];
    __shared__ float l1[RR * VV];    // 200
    __shared__ float l2[RR * VV];

    for (int i = tid; i < CC * VV; i += 256) lxm[i] = xm[(size_t)n * CC * VV + i];
    __syncthreads();

    if (tid < VV) {
        float s = 0.f;
        for (int c = 0; c < CC; c++) s += lxm[c * VV + tid];
        ls[tid] = s * (1.f / CC);
    }
    if (tid < RR * VV) {
        int r = tid / VV, v = tid % VV;
        float s1 = b1[r], s2 = b2[r];
        for (int c = 0; c < CC; c++) {
            float xv = lxm[c * VV + v];
            s1 += w1[r * CC + c] * xv;
            s2 += w2[r * CC + c] * xv;
        }
        l1[tid] = s1;
        l2[tid] = s2;
    }
    __syncthreads();

    if (tid < HH) {
        float h = sb1[tid];
        for (int v = 0; v < VV; v++) h += sw1[tid * VV + v] * ls[v];
        lh[tid] = fmaxf(h, 0.f);
    }
    __syncthreads();

    if (tid < VV) {
        float z = sb2[tid];
        for (int j = 0; j < HH; j++) z += sw2[tid * HH + j] * lh[j];
        a_out[(size_t)n * VV + tid] = 1.f / (1.f + expf(-z));
    }

    // rel: 8*25*25 = 5000 elements
    for (int idx = tid; idx < RR * VV * VV; idx += 256) {
        int r = idx / (VV * VV);
        int rem = idx % (VV * VV);
        int u = rem / VV, v = rem % VV;
        rel_out[(size_t)n * RR * VV * VV + idx] = tanhf(l1[r * VV + u] - l2[r * VV + v]);
    }
}

// ---------------------------------------------------------------------------
// Kernel C: per-(n,c) output tile.
//  Ad'[u,v] = (b4[c] + A[u,v] + sum_r w4[c,r]*rel[n,r,u,v]) * a[n,v]
//  out[t,u] = sum_v Ad'[u,v] * x[n,c,t,v]
// LDS: ad padded to 28x28 (rows 25..27 zero), xs padded 128x28 (cols 25..27 0).
// Phase 2: 4x4 register tile per thread, float4 LDS reads.
// ---------------------------------------------------------------------------
__global__ __launch_bounds__(256) void kC_main(
    const float* __restrict__ x, const float* __restrict__ A,
    const float* __restrict__ w4, const float* __restrict__ b4,
    const float* __restrict__ rel, const float* __restrict__ av,
    float* __restrict__ out) {
    const int blk = blockIdx.x;    // n*CC + c
    const int n = blk / CC;
    const int c = blk % CC;
    const int tid = threadIdx.x;

    __shared__ float ad[28 * 28];       // 3136 floats
    __shared__ float xs[TT * 28];       // 3584 floats

    float w4r[RR];
#pragma unroll
    for (int r = 0; r < RR; r++) w4r[r] = w4[c * RR + r];
    const float b4c = b4[c];

    // phase 1: Ad'
    for (int uv = tid; uv < 28 * 28; uv += 256) {
        int u = uv / 28, v = uv % 28;
        float val = 0.f;
        if (u < VV && v < VV) {
            val = b4c + A[u * VV + v];
            const float* rp = rel + (size_t)n * RR * VV * VV + u * VV + v;
#pragma unroll
            for (int r = 0; r < RR; r++) val += w4r[r] * rp[r * VV * VV];
            val *= av[(size_t)n * VV + v];
        }
        ad[uv] = val;
    }

    // phase 1b: stage x tile (coalesced global read, padded LDS write)
    const float* xb = x + (size_t)blk * (TT * VV);
    for (int idx = tid; idx < TT * VV; idx += 256) {
        int t = idx / VV, v = idx % VV;
        xs[t * 28 + v] = xb[idx];
    }
    for (int j = tid; j < TT * 3; j += 256) {
        int t = j / 3, v = VV + j % 3;
        xs[t * 28 + v] = 0.f;
    }
    __syncthreads();

    // phase 2: 4x4 register tile
    const int ug = tid % 7;        // 7 u-groups of 4 -> covers 28 (25 valid)
    const int tg = tid / 7;        // need 32 t-groups of 4
    if (tg < 32) {
        const int u0 = ug * 4;
        const int t0 = tg * 4;
        float acc[4][4] = {};
#pragma unroll
        for (int vb = 0; vb < 7; vb++) {
            float4 a4[4], x4[4];
#pragma unroll
            for (int j = 0; j < 4; j++) a4[j] = *(const float4*)&ad[(u0 + j) * 28 + vb * 4];
#pragma unroll
            for (int i = 0; i < 4; i++) x4[i] = *(const float4*)&xs[(t0 + i) * 28 + vb * 4];
#pragma unroll
            for (int i = 0; i < 4; i++) {
#pragma unroll
                for (int j = 0; j < 4; j++) {
                    acc[i][j] += a4[j].x * x4[i].x;
                    acc[i][j] += a4[j].y * x4[i].y;
                    acc[i][j] += a4[j].z * x4[i].z;
                    acc[i][j] += a4[j].w * x4[i].w;
                }
            }
        }
        float* ob = out + (size_t)blk * (TT * VV);
#pragma unroll
        for (int i = 0; i < 4; i++) {
#pragma unroll
            for (int j = 0; j < 4; j++) {
                int u = u0 + j;
                if (u < VV) ob[(t0 + i) * VV + u] = acc[i][j];
            }
        }
    }
}

// ---------------------------------------------------------------------------
extern "C" void kernel_launch(void* const* d_in, const int* in_sizes, int n_in,
                              void* d_out, int out_size, void* d_ws, size_t ws_size,
                              hipStream_t stream) {
    const float* x   = (const float*)d_in[0];
    const float* A   = (const float*)d_in[1];
    const float* w1  = (const float*)d_in[2];
    const float* b1  = (const float*)d_in[3];
    const float* w2  = (const float*)d_in[4];
    const float* b2  = (const float*)d_in[5];
    const float* w4  = (const float*)d_in[6];
    const float* b4  = (const float*)d_in[7];
    const float* sw1 = (const float*)d_in[8];
    const float* sb1 = (const float*)d_in[9];
    const float* sw2 = (const float*)d_in[10];
    const float* sb2 = (const float*)d_in[11];
    float* out = (float*)d_out;

    float* ws = (float*)d_ws;
    float* xm  = ws;                                 // N*C*V   = 204800
    float* a_s = xm + (size_t)NN * CC * VV;          // N*V     = 3200
    float* rel = a_s + (size_t)NN * VV;              // N*R*V*V = 640000

    kA_tmean<<<NN * CC, 256, 0, stream>>>(x, xm);
    kB_small<<<NN, 256, 0, stream>>>(xm, w1, b1, w2, b2, sw1, sb1, sw2, sb2, a_s, rel);
    kC_main<<<NN * CC, 256, 0, stream>>>(x, A, w4, b4, rel, a_s, out);
}

// Round 2
// 315.555 us; speedup vs baseline: 1.3415x; 1.3415x over previous
//
#include <hip/hip_runtime.h>
#include <hip/hip_bf16.h>

// Problem constants
#define NN 128
#define CC 64
#define TT 128
#define VV 25
#define RR 8
#define HH 12
#define TPAD 132   // xs row stride (dwords): %4==0 for b128 align; /4=33 odd -> quads cycle all 8

// ---------------------------------------------------------------------------
// Kernel A: xm[n,c,v] = mean over T of x[n,c,t,v].  One block per (n,c).
// Stage tile in LDS (b128, conflict-free), column-reduce with strided reads
// (bank = v + 16*tseg -> <=2-way, free), tree finish. No atomics.
// ---------------------------------------------------------------------------
__global__ __launch_bounds__(256) void kA_tmean(const float* __restrict__ x,
                                                float* __restrict__ xm) {
    const int blk = blockIdx.x;            // n*CC + c
    const int tid = threadIdx.x;
    __shared__ float st[TT * VV];          // 3200 floats
    __shared__ float ps[8 * VV];

    const float4* xb4 = (const float4*)(x + (size_t)blk * (TT * VV));
    float4* st4 = (float4*)st;
    for (int i = tid; i < (TT * VV) / 4; i += 256) st4[i] = xb4[i];
    __syncthreads();

    if (tid < 200) {
        const int v = tid % VV, tseg = tid / VV;   // 8 segments of 16 t
        float s = 0.f;
        const int base = tseg * 16 * VV + v;
#pragma unroll
        for (int i = 0; i < 16; i++) s += st[base + i * VV];
        ps[tseg * VV + v] = s;
    }
    __syncthreads();
    if (tid < VV) {
        float s = 0.f;
#pragma unroll
        for (int k = 0; k < 8; k++) s += ps[k * VV + tid];
        xm[(size_t)blk * VV + tid] = s * (1.f / TT);
    }
}

// ---------------------------------------------------------------------------
// Kernel B: per-n small pipeline (unchanged). One block per n.
// ---------------------------------------------------------------------------
__global__ __launch_bounds__(256) void kB_small(
    const float* __restrict__ xm,
    const float* __restrict__ w1, const float* __restrict__ b1,
    const float* __restrict__ w2, const float* __restrict__ b2,
    const float* __restrict__ sw1, const float* __restrict__ sb1,
    const float* __restrict__ sw2, const float* __restrict__ sb2,
    float* __restrict__ a_out, float* __restrict__ rel_out) {
    const int n = blockIdx.x;
    const int tid = threadIdx.x;
    __shared__ float lxm[CC * VV];   // 1600
    __shared__ float ls[VV];
    __shared__ float lh[HH];
    __shared__ float l1[RR * VV];
    __shared__ float l2[RR * VV];

    for (int i = tid; i < CC * VV; i += 256) lxm[i] = xm[(size_t)n * CC * VV + i];
    __syncthreads();

    if (tid < VV) {
        float s = 0.f;
        for (int c = 0; c < CC; c++) s += lxm[c * VV + tid];
        ls[tid] = s * (1.f / CC);
    }
    if (tid < RR * VV) {
        int r = tid / VV, v = tid % VV;
        float s1 = b1[r], s2 = b2[r];
        for (int c = 0; c < CC; c++) {
            float xv = lxm[c * VV + v];
            s1 += w1[r * CC + c] * xv;
            s2 += w2[r * CC + c] * xv;
        }
        l1[tid] = s1;
        l2[tid] = s2;
    }
    __syncthreads();

    if (tid < HH) {
        float h = sb1[tid];
        for (int v = 0; v < VV; v++) h += sw1[tid * VV + v] * ls[v];
        lh[tid] = fmaxf(h, 0.f);
    }
    __syncthreads();

    if (tid < VV) {
        float z = sb2[tid];
        for (int j = 0; j < HH; j++) z += sw2[tid * HH + j] * lh[j];
        a_out[(size_t)n * VV + tid] = 1.f / (1.f + expf(-z));
    }

    for (int idx = tid; idx < RR * VV * VV; idx += 256) {
        int r = idx / (VV * VV);
        int rem = idx % (VV * VV);
        int u = rem / VV, v = rem % VV;
        rel_out[(size_t)n * RR * VV * VV + idx] = tanhf(l1[r * VV + u] - l2[r * VV + v]);
    }
}

// ---------------------------------------------------------------------------
// Kernel C: per-(n,c) output tile.
//  Ad'[u,v] = (b4[c] + A[u,v] + sum_r w4[c,r]*rel[n,r,u,v]) * a[n,v]
//  out[t,u] = sum_v Ad'[u,v] * x[n,c,t,v]
// LDS: ad[28][28] (cols v>=25 zero), xs TRANSPOSED [v][t] stride TPAD=132
// (rows v>=25 zero). Thread map: ug=tid>>5 (7 u-groups of 4), tg=tid&31
// (32 t-groups of 4). a4 reads: 2 distinct addrs/wave -> broadcast-free.
// x4 reads: 32 consecutive-quad addrs -> conflict-free (bandwidth floor).
// ---------------------------------------------------------------------------
__global__ __launch_bounds__(256) void kC_main(
    const float* __restrict__ x, const float* __restrict__ A,
    const float* __restrict__ w4, const float* __restrict__ b4,
    const float* __restrict__ rel, const float* __restrict__ av,
    float* __restrict__ out) {
    const int blk = blockIdx.x;    // n*CC + c
    const int n = blk / CC;
    const int c = blk % CC;
    const int tid = threadIdx.x;

    __shared__ float ad[28 * 28];       // 12544 B
    __shared__ float xs[28 * TPAD];     // 14784 B

    float w4r[RR];
#pragma unroll
    for (int r = 0; r < RR; r++) w4r[r] = w4[c * RR + r];
    const float b4c = b4[c];

    // phase 1: Ad' (scaled by SE attention a[v])
    for (int uv = tid; uv < 28 * 28; uv += 256) {
        int u = uv / 28, v = uv % 28;
        float val = 0.f;
        if (u < VV && v < VV) {
            val = b4c + A[u * VV + v];
            const float* rp = rel + (size_t)n * RR * VV * VV + u * VV + v;
#pragma unroll
            for (int r = 0; r < RR; r++) val += w4r[r] * rp[r * VV * VV];
            val *= av[(size_t)n * VV + v];
        }
        ad[uv] = val;
    }

    // phase 1b: stage x tile TRANSPOSED (coalesced global float4 read,
    // scalar LDS writes xs[v][t]; ~4-8 way write conflicts, cheap)
    const float4* xb4 = (const float4*)(x + (size_t)blk * (TT * VV));
    for (int i = tid; i < (TT * VV) / 4; i += 256) {
        float4 q = xb4[i];
        int lin = i * 4;
        float vals[4] = {q.x, q.y, q.z, q.w};
#pragma unroll
        for (int k = 0; k < 4; k++) {
            int l = lin + k;
            int t = l / VV, v = l - t * VV;
            xs[v * TPAD + t] = vals[k];
        }
    }
    // zero pad rows v = 25..27 (they multiply ad cols that are zero, but
    // avoid NaN from uninit LDS)
    for (int i = tid; i < 3 * TPAD; i += 256) xs[25 * TPAD + i] = 0.f;
    __syncthreads();

    // phase 2: 4x4 register tile, conflict-free LDS reads
    const int ug = tid >> 5;       // 0..7 (active < 7)
    const int tg = tid & 31;       // 0..31
    if (ug < 7) {
        const int u0 = ug * 4;
        const int t0 = tg * 4;
        float acc[4][4] = {};      // acc[dt][j]
#pragma unroll
        for (int vb = 0; vb < 7; vb++) {
            float4 a4[4];          // a4[j] = ad[u0+j][vb*4 .. +3]
            float4 x4[4];          // x4[vi] = xs[vb*4+vi][t0 .. t0+3]  (over t!)
#pragma unroll
            for (int j = 0; j < 4; j++) a4[j] = *(const float4*)&ad[(u0 + j) * 28 + vb * 4];
#pragma unroll
            for (int vi = 0; vi < 4; vi++) x4[vi] = *(const float4*)&xs[(vb * 4 + vi) * TPAD + t0];
            const float* xv = (const float*)&x4[0];
#pragma unroll
            for (int dt = 0; dt < 4; dt++) {
#pragma unroll
                for (int j = 0; j < 4; j++) {
                    acc[dt][j] += a4[j].x * xv[0 * 4 + dt];
                    acc[dt][j] += a4[j].y * xv[1 * 4 + dt];
                    acc[dt][j] += a4[j].z * xv[2 * 4 + dt];
                    acc[dt][j] += a4[j].w * xv[3 * 4 + dt];
                }
            }
        }
        float* ob = out + (size_t)blk * (TT * VV);
#pragma unroll
        for (int dt = 0; dt < 4; dt++) {
#pragma unroll
            for (int j = 0; j < 4; j++) {
                int u = u0 + j;
                if (u < VV) ob[(t0 + dt) * VV + u] = acc[dt][j];
            }
        }
    }
}

// ---------------------------------------------------------------------------
extern "C" void kernel_launch(void* const* d_in, const int* in_sizes, int n_in,
                              void* d_out, int out_size, void* d_ws, size_t ws_size,
                              hipStream_t stream) {
    const float* x   = (const float*)d_in[0];
    const float* A   = (const float*)d_in[1];
    const float* w1  = (const float*)d_in[2];
    const float* b1  = (const float*)d_in[3];
    const float* w2  = (const float*)d_in[4];
    const float* b2  = (const float*)d_in[5];
    const float* w4  = (const float*)d_in[6];
    const float* b4  = (const float*)d_in[7];
    const float* sw1 = (const float*)d_in[8];
    const float* sb1 = (const float*)d_in[9];
    const float* sw2 = (const float*)d_in[10];
    const float* sb2 = (const float*)d_in[11];
    float* out = (float*)d_out;

    float* ws = (float*)d_ws;
    float* xm  = ws;                                 // N*C*V   = 204800
    float* a_s = xm + (size_t)NN * CC * VV;          // N*V     = 3200
    float* rel = a_s + (size_t)NN * VV;              // N*R*V*V = 640000

    kA_tmean<<<NN * CC, 256, 0, stream>>>(x, xm);
    kB_small<<<NN, 256, 0, stream>>>(xm, w1, b1, w2, b2, sw1, sb1, sw2, sb2, a_s, rel);
    kC_main<<<NN * CC, 256, 0, stream>>>(x, A, w4, b4, rel, a_s, out);
}

// Round 3
// 248.700 us; speedup vs baseline: 1.7021x; 1.2688x over previous
//
#include <hip/hip_runtime.h>
#include <hip/hip_bf16.h>

// Problem constants
#define NN 128
#define CC 64
#define TT 128
#define VV 25
#define RR 8
#define HH 12
#define TPAD 132   // xs row stride (dwords): %4==0 for b128 align; /4=33 odd -> quads cycle all 8

// ---------------------------------------------------------------------------
// Kernel A: xm[n,c,v] = mean over T of x[n,c,t,v].  One block per (n,c).
// Stage tile in LDS (b128, conflict-free), column-reduce with strided reads
// (<=2-way, free), tree finish. No atomics.
// ---------------------------------------------------------------------------
__global__ __launch_bounds__(256) void kA_tmean(const float* __restrict__ x,
                                                float* __restrict__ xm) {
    const int blk = blockIdx.x;            // n*CC + c
    const int tid = threadIdx.x;
    __shared__ float st[TT * VV];          // 3200 floats
    __shared__ float ps[8 * VV];

    const float4* xb4 = (const float4*)(x + (size_t)blk * (TT * VV));
    float4* st4 = (float4*)st;
    for (int i = tid; i < (TT * VV) / 4; i += 256) st4[i] = xb4[i];
    __syncthreads();

    if (tid < 200) {
        const int v = tid % VV, tseg = tid / VV;   // 8 segments of 16 t
        float s = 0.f;
        const int base = tseg * 16 * VV + v;
#pragma unroll
        for (int i = 0; i < 16; i++) s += st[base + i * VV];
        ps[tseg * VV + v] = s;
    }
    __syncthreads();
    if (tid < VV) {
        float s = 0.f;
#pragma unroll
        for (int k = 0; k < 8; k++) s += ps[k * VV + tid];
        xm[(size_t)blk * VV + tid] = s * (1.f / TT);
    }
}

// ---------------------------------------------------------------------------
// Kernel B: per-n small pipeline. One block per n.
// ---------------------------------------------------------------------------
__global__ __launch_bounds__(256) void kB_small(
    const float* __restrict__ xm,
    const float* __restrict__ w1, const float* __restrict__ b1,
    const float* __restrict__ w2, const float* __restrict__ b2,
    const float* __restrict__ sw1, const float* __restrict__ sb1,
    const float* __restrict__ sw2, const float* __restrict__ sb2,
    float* __restrict__ a_out, float* __restrict__ rel_out) {
    const int n = blockIdx.x;
    const int tid = threadIdx.x;
    __shared__ float lxm[CC * VV];   // 1600
    __shared__ float ls[VV];
    __shared__ float lh[HH];
    __shared__ float l1[RR * VV];
    __shared__ float l2[RR * VV];

    for (int i = tid; i < CC * VV; i += 256) lxm[i] = xm[(size_t)n * CC * VV + i];
    __syncthreads();

    if (tid < VV) {
        float s = 0.f;
        for (int c = 0; c < CC; c++) s += lxm[c * VV + tid];
        ls[tid] = s * (1.f / CC);
    }
    if (tid < RR * VV) {
        int r = tid / VV, v = tid % VV;
        float s1 = b1[r], s2 = b2[r];
        for (int c = 0; c < CC; c++) {
            float xv = lxm[c * VV + v];
            s1 += w1[r * CC + c] * xv;
            s2 += w2[r * CC + c] * xv;
        }
        l1[tid] = s1;
        l2[tid] = s2;
    }
    __syncthreads();

    if (tid < HH) {
        float h = sb1[tid];
        for (int v = 0; v < VV; v++) h += sw1[tid * VV + v] * ls[v];
        lh[tid] = fmaxf(h, 0.f);
    }
    __syncthreads();

    if (tid < VV) {
        float z = sb2[tid];
        for (int j = 0; j < HH; j++) z += sw2[tid * HH + j] * lh[j];
        a_out[(size_t)n * VV + tid] = 1.f / (1.f + expf(-z));
    }

    for (int idx = tid; idx < RR * VV * VV; idx += 256) {
        int r = idx / (VV * VV);
        int rem = idx % (VV * VV);
        int u = rem / VV, v = rem % VV;
        rel_out[(size_t)n * RR * VV * VV + idx] = tanhf(l1[r * VV + u] - l2[r * VV + v]);
    }
}

// ---------------------------------------------------------------------------
// Kernel C: per-(n,c) output tile.
//  Ad'[u,v] = (b4[c] + A[u,v] + sum_r w4[c,r]*rel[n,r,u,v]) * a[n,v]
//  out[t,u] = sum_v Ad'[u,v] * x[n,c,t,v]
// LDS: ad[28][28] (rows/cols >=25 zero), xs TRANSPOSED [v][t] stride TPAD=132.
// Phase 2: 4x4 register tile, conflict-free/broadcast LDS reads.
// Epilogue: acc -> LDS (exact output-tile layout, reusing xs) -> coalesced
// float4 global stores. (R2 lesson: direct scalar stores with 400 B lane
// stride cost ~48 cyc/instr in TA coalescing — that WAS the kernel.)
// ---------------------------------------------------------------------------
__global__ __launch_bounds__(256) void kC_main(
    const float* __restrict__ x, const float* __restrict__ A,
    const float* __restrict__ w4, const float* __restrict__ b4,
    const float* __restrict__ rel, const float* __restrict__ av,
    float* __restrict__ out) {
    const int blk = blockIdx.x;    // n*CC + c
    const int n = blk / CC;
    const int c = blk % CC;
    const int tid = threadIdx.x;

    __shared__ float ad[28 * 28];       // 12544 B
    __shared__ float xs[28 * TPAD];     // 14784 B (>= 3200 for os reuse)
    float* os = xs;                     // output staging, reuses xs after phase 2

    float w4r[RR];
#pragma unroll
    for (int r = 0; r < RR; r++) w4r[r] = w4[c * RR + r];
    const float b4c = b4[c];

    // phase 1: Ad' (scaled by SE attention a[v])
    for (int uv = tid; uv < 28 * 28; uv += 256) {
        int u = uv / 28, v = uv % 28;
        float val = 0.f;
        if (u < VV && v < VV) {
            val = b4c + A[u * VV + v];
            const float* rp = rel + (size_t)n * RR * VV * VV + u * VV + v;
#pragma unroll
            for (int r = 0; r < RR; r++) val += w4r[r] * rp[r * VV * VV];
            val *= av[(size_t)n * VV + v];
        }
        ad[uv] = val;
    }

    // phase 1b: stage x tile TRANSPOSED (coalesced global float4 read,
    // scalar LDS writes xs[v][t]; ~4-way write conflicts, cheap)
    const float4* xb4 = (const float4*)(x + (size_t)blk * (TT * VV));
    for (int i = tid; i < (TT * VV) / 4; i += 256) {
        float4 q = xb4[i];
        int lin = i * 4;
        float vals[4] = {q.x, q.y, q.z, q.w};
#pragma unroll
        for (int k = 0; k < 4; k++) {
            int l = lin + k;
            int t = l / VV, v = l - t * VV;
            xs[v * TPAD + t] = vals[k];
        }
    }
    for (int i = tid; i < 3 * TPAD; i += 256) xs[25 * TPAD + i] = 0.f;
    __syncthreads();

    // phase 2: 4x4 register tile
    const int ug = tid >> 5;       // 0..7 (active < 7)
    const int tg = tid & 31;       // 0..31
    const int u0 = ug * 4;
    const int t0 = tg * 4;
    float acc[4][4];               // acc[dt][j]
#pragma unroll
    for (int dt = 0; dt < 4; dt++)
#pragma unroll
        for (int j = 0; j < 4; j++) acc[dt][j] = 0.f;

    if (ug < 7) {
#pragma unroll
        for (int vb = 0; vb < 7; vb++) {
            float4 a4[4];          // a4[j] = ad[u0+j][vb*4 .. +3]  (broadcast)
            float4 x4[4];          // x4[vi] = xs[vb*4+vi][t0 .. t0+3]
#pragma unroll
            for (int j = 0; j < 4; j++) a4[j] = *(const float4*)&ad[(u0 + j) * 28 + vb * 4];
#pragma unroll
            for (int vi = 0; vi < 4; vi++) x4[vi] = *(const float4*)&xs[(vb * 4 + vi) * TPAD + t0];
            const float* xv = (const float*)&x4[0];
#pragma unroll
            for (int dt = 0; dt < 4; dt++) {
#pragma unroll
                for (int j = 0; j < 4; j++) {
                    acc[dt][j] += a4[j].x * xv[0 * 4 + dt];
                    acc[dt][j] += a4[j].y * xv[1 * 4 + dt];
                    acc[dt][j] += a4[j].z * xv[2 * 4 + dt];
                    acc[dt][j] += a4[j].w * xv[3 * 4 + dt];
                }
            }
        }
    }
    __syncthreads();   // all xs reads done; safe to overwrite with os

    // epilogue a: scatter acc into os with exact output-tile layout
    if (ug < 7) {
#pragma unroll
        for (int dt = 0; dt < 4; dt++) {
#pragma unroll
            for (int j = 0; j < 4; j++) {
                int u = u0 + j;
                if (u < VV) os[(t0 + dt) * VV + u] = acc[dt][j];
            }
        }
    }
    __syncthreads();

    // epilogue b: coalesced float4 stores of the whole 12.8 KB tile
    float4* ob4 = (float4*)(out + (size_t)blk * (TT * VV));
    const float4* os4 = (const float4*)os;
    for (int i = tid; i < (TT * VV) / 4; i += 256) ob4[i] = os4[i];
}

// ---------------------------------------------------------------------------
extern "C" void kernel_launch(void* const* d_in, const int* in_sizes, int n_in,
                              void* d_out, int out_size, void* d_ws, size_t ws_size,
                              hipStream_t stream) {
    const float* x   = (const float*)d_in[0];
    const float* A   = (const float*)d_in[1];
    const float* w1  = (const float*)d_in[2];
    const float* b1  = (const float*)d_in[3];
    const float* w2  = (const float*)d_in[4];
    const float* b2  = (const float*)d_in[5];
    const float* w4  = (const float*)d_in[6];
    const float* b4  = (const float*)d_in[7];
    const float* sw1 = (const float*)d_in[8];
    const float* sb1 = (const float*)d_in[9];
    const float* sw2 = (const float*)d_in[10];
    const float* sb2 = (const float*)d_in[11];
    float* out = (float*)d_out;

    float* ws = (float*)d_ws;
    float* xm  = ws;                                 // N*C*V   = 204800
    float* a_s = xm + (size_t)NN * CC * VV;          // N*V     = 3200
    float* rel = a_s + (size_t)NN * VV;              // N*R*V*V = 640000

    kA_tmean<<<NN * CC, 256, 0, stream>>>(x, xm);
    kB_small<<<NN, 256, 0, stream>>>(xm, w1, b1, w2, b2, sw1, sb1, sw2, sb2, a_s, rel);
    kC_main<<<NN * CC, 256, 0, stream>>>(x, A, w4, b4, rel, a_s, out);
}